// Round 4
// baseline (312.516 us; speedup 1.0000x reference)
//
#include <hip/hip_runtime.h>
#include <hip/hip_bf16.h>
#include <math.h>

// MoE gate: B=524288 tokens, E=32, H=4, D=8, NE=64 experts, TOP_K=2.
// Everything up to expert_weight depends ONLY on taskID in [0,6) ->
// precompute clean_logits[6][64] and noise_std[6][64] once (kernel 1),
// then the per-token work is a pure streaming kernel (kernel 2), plus a
// deterministic tree reduction for `load` (kernel 3).
//
// R1/R2 changes vs R0 (latency-bound at 38% occupancy, 2.5 TB/s):
//  - grid 1024->2048, __launch_bounds__(256,8): 8 blocks/CU = 32 waves/CU
//  - 8 lanes/row (2x float4/lane): 2x load ILP, merge steps 4->3
//  - u64 sortable keys for top-2 (value desc, index asc) -> cheap max/min merge
//  - nontemporal gates stores via clang ext_vector_type (fixes R1 compile err)
// R3: identical to R2 (R2 never ran — broker timeout).

#define NE 64
#define NTASK 6
#define GRID_MAIN 2048
#define BLOCK_MAIN 256

typedef float f32x4 __attribute__((ext_vector_type(4)));

// ---------------------------------------------------------------------------
// Kernel 1: per-task tables. One block, 384 threads (6 waves = 6 tasks).
// ---------------------------------------------------------------------------
__global__ __launch_bounds__(384)
void moe_tables(const float* __restrict__ embed_table,
                const float* __restrict__ expert_keys,
                const float* __restrict__ Wq, const float* __restrict__ bq,
                const float* __restrict__ Wk, const float* __restrict__ bk,
                const float* __restrict__ Wg, const float* __restrict__ bg,
                const float* __restrict__ Wn, const float* __restrict__ bn,
                float* __restrict__ tbl /* [6][2][64]: clean, noise_std */)
{
    __shared__ float s_ek[1024];   // expert_keys 32x32
    __shared__ float s_wk[1024];   // Wk 32x32
    __shared__ float s_k[1024];    // k[s][e] = expert_keys @ Wk^T + bk (task-indep)
    __shared__ float s_q[NTASK][32];
    __shared__ float s_sc[NTASK][4][32];
    __shared__ float s_ew[NTASK][32];

    const int tid  = threadIdx.x;      // 0..383
    const int wave = tid >> 6;         // task id 0..5
    const int lane = tid & 63;

    for (int i = tid; i < 1024; i += 384) { s_ek[i] = expert_keys[i]; s_wk[i] = Wk[i]; }
    __syncthreads();

    // k = expert_keys @ Wk^T + bk  (shared by all tasks)
    for (int i = tid; i < 1024; i += 384) {
        int s = i >> 5, e = i & 31;
        float acc = bk[e];
        for (int j = 0; j < 32; ++j) acc += s_ek[s*32 + j] * s_wk[e*32 + j];
        s_k[i] = acc;
    }
    __syncthreads();

    // q_t = (embed[t] @ Wq^T + bq) * 1/sqrt(D)
    if (lane < 32) {
        float acc = bq[lane];
        for (int j = 0; j < 32; ++j) acc += embed_table[wave*32 + j] * Wq[lane*32 + j];
        s_q[wave][lane] = acc * 0.35355339059327373f;  // 1/sqrt(8)
    }
    __syncthreads();

    // scores[h][s] = sum_d q[h*8+d] * k[s][h*8+d]
    for (int r = lane; r < 128; r += 64) {
        int h = r >> 5, s = r & 31;
        float acc = 0.f;
        for (int d = 0; d < 8; ++d) acc += s_q[wave][h*8 + d] * s_k[s*32 + h*8 + d];
        s_sc[wave][h][s] = acc;
    }
    __syncthreads();

    // per-head softmax over the 32 experts
    if (lane < 4) {
        int h = lane;
        float m = -1e30f;
        for (int s = 0; s < 32; ++s) m = fmaxf(m, s_sc[wave][h][s]);
        float sum = 0.f;
        for (int s = 0; s < 32; ++s) { float e = expf(s_sc[wave][h][s] - m); s_sc[wave][h][s] = e; sum += e; }
        float inv = 1.f / sum;
        for (int s = 0; s < 32; ++s) s_sc[wave][h][s] *= inv;
    }
    __syncthreads();

    // mean over heads, softmax over experts -> expert_weight
    if (lane == 0) {
        float aw[32];
        float m = -1e30f;
        for (int s = 0; s < 32; ++s) {
            float a = 0.25f * (s_sc[wave][0][s] + s_sc[wave][1][s] +
                               s_sc[wave][2][s] + s_sc[wave][3][s]);
            aw[s] = a; m = fmaxf(m, a);
        }
        float sum = 0.f;
        for (int s = 0; s < 32; ++s) { float e = expf(aw[s] - m); aw[s] = e; sum += e; }
        float inv = 1.f / sum;
        for (int s = 0; s < 32; ++s) s_ew[wave][s] = aw[s] * inv;
    }
    __syncthreads();

    // clean_logits and noise_std per expert (64 outputs, one per lane)
    {
        int j = lane;   // 0..63
        float c = bg[j], n = bn[j];
        for (int s = 0; s < 32; ++s) {
            float w = s_ew[wave][s];
            c += w * Wg[j*32 + s];
            n += w * Wn[j*32 + s];
        }
        // softplus(x) = max(x,0) + log1p(exp(-|x|))
        float sp = fmaxf(n, 0.f) + log1pf(expf(-fabsf(n)));
        tbl[(wave*2    )*64 + j] = c;            // stbl layout: t*128 + j
        tbl[(wave*2 + 1)*64 + j] = sp + 0.01f;   // t*128 + 64 + j (NOISE_EPS)
    }
}

// ---------------------------------------------------------------------------
// Kernel 2: streaming gate kernel. 8 lanes per row; lane gl owns 8 consecutive
// columns [gl*8, gl*8+8) -> two float4 loads/stores per lane, coalesced.
// Top-2 via u64 sortable keys: key = (sortable(v)<<32) | (63-idx), so
// max-key == (value desc, index asc) — the jax.lax.top_k tie rule.
// ---------------------------------------------------------------------------
__device__ __forceinline__ unsigned long long mkkey(float f, int idx) {
    unsigned u  = __float_as_uint(f);
    unsigned su = (u & 0x80000000u) ? ~u : (u | 0x80000000u);
    return ((unsigned long long)su << 32) | (unsigned)(63 - idx);
}
__device__ __forceinline__ float keyval(unsigned long long k) {
    unsigned su = (unsigned)(k >> 32);
    unsigned u  = (su & 0x80000000u) ? (su ^ 0x80000000u) : ~su;
    return __uint_as_float(u);
}
__device__ __forceinline__ unsigned long long umax64(unsigned long long a, unsigned long long b) { return a > b ? a : b; }
__device__ __forceinline__ unsigned long long umin64(unsigned long long a, unsigned long long b) { return a < b ? a : b; }

__global__ __launch_bounds__(BLOCK_MAIN, 8)
void moe_gate(const int* __restrict__ taskID,
              const float* __restrict__ noise,
              const float* __restrict__ tbl,
              float* __restrict__ gates,
              float* __restrict__ partials,
              int B)
{
    __shared__ float stbl[NTASK*128];    // 3 KiB: [task][clean[64] | std[64]]
    __shared__ float sload[NE];

    const int tid = threadIdx.x;
    for (int i = tid; i < NTASK*128; i += BLOCK_MAIN) stbl[i] = tbl[i];
    if (tid < NE) sload[tid] = 0.f;
    __syncthreads();

    const int sub = tid >> 3;         // 0..31: row slot within block
    const int gl  = tid & 7;          // lane within 8-lane row group
    const int c0  = gl * 8;           // first of 8 owned columns

    const long stride = (long)gridDim.x * 32;
    for (long row = (long)blockIdx.x * 32 + sub; row < B; row += stride) {
        const int t = taskID[row];
        const float* cl = &stbl[t * 128];

        const float4* np = (const float4*)(noise + row * 64 + c0);
        float4 nz0 = np[0];
        float4 nz1 = np[1];
        float4 cc0 = *(const float4*)(cl + c0);
        float4 cc1 = *(const float4*)(cl + c0 + 4);
        float4 ss0 = *(const float4*)(cl + 64 + c0);
        float4 ss1 = *(const float4*)(cl + 64 + c0 + 4);

        float v[8];
        v[0] = fmaf(nz0.x, ss0.x, cc0.x);
        v[1] = fmaf(nz0.y, ss0.y, cc0.y);
        v[2] = fmaf(nz0.z, ss0.z, cc0.z);
        v[3] = fmaf(nz0.w, ss0.w, cc0.w);
        v[4] = fmaf(nz1.x, ss1.x, cc1.x);
        v[5] = fmaf(nz1.y, ss1.y, cc1.y);
        v[6] = fmaf(nz1.z, ss1.z, cc1.z);
        v[7] = fmaf(nz1.w, ss1.w, cc1.w);

        // local top-2 of 8 (keys all > 0 for finite inputs)
        unsigned long long k1 = mkkey(v[0], c0), k2 = 0ull;
        #pragma unroll
        for (int j = 1; j < 8; ++j) {
            unsigned long long k = mkkey(v[j], c0 + j);
            if (k > k1)      { k2 = k1; k1 = k; }
            else if (k > k2) { k2 = k; }
        }

        // butterfly merge across the 8-lane group (masks 1,2,4 stay in-group)
        #pragma unroll
        for (int m = 1; m < 8; m <<= 1) {
            unsigned long long p1 = __shfl_xor((unsigned long long)k1, m);
            unsigned long long p2 = __shfl_xor((unsigned long long)k2, m);
            unsigned long long hi = umax64(k1, p1);
            unsigned long long lo = umin64(k1, p1);
            k2 = umax64(lo, umax64(k2, p2));
            k1 = hi;
        }

        const int i1 = 63 - (int)(k1 & 63u);
        const int i2 = 63 - (int)(k2 & 63u);
        const float v1 = keyval(k1);
        const float v2 = keyval(k2);

        const float e   = expf(v2 - v1);
        const float inv = 1.f / (1.f + e);
        const float g1  = inv, g2 = e * inv;

        float o[8];
        #pragma unroll
        for (int j = 0; j < 8; ++j) {
            const int col = c0 + j;
            o[j] = (col == i1) ? g1 : ((col == i2) ? g2 : 0.f);
        }
        f32x4 o0 = { o[0], o[1], o[2], o[3] };
        f32x4 o1 = { o[4], o[5], o[6], o[7] };
        __builtin_nontemporal_store(o0, (f32x4*)(gates + row * 64 + c0));
        __builtin_nontemporal_store(o1, (f32x4*)(gates + row * 64 + c0 + 4));

        if (gl == 0) {
            atomicAdd(&sload[i1], g1);
            atomicAdd(&sload[i2], g2);
        }
    }
    __syncthreads();
    if (tid < NE) partials[(long)blockIdx.x * NE + tid] = sload[tid];
}

// ---------------------------------------------------------------------------
// Kernel 3: deterministic reduction of per-block partials -> load[64].
// ---------------------------------------------------------------------------
__global__ __launch_bounds__(1024)
void moe_load_reduce(const float* __restrict__ partials,
                     float* __restrict__ load, int nparts)
{
    __shared__ float s[1024];
    const int tid  = threadIdx.x;       // 0..1023
    const int bin  = tid & 63;
    const int part = tid >> 6;          // 0..15
    const int per  = nparts >> 4;       // partials per group
    float acc = 0.f;
    for (int p = part * per; p < (part + 1) * per; ++p)
        acc += partials[(long)p * NE + bin];
    s[part * 64 + bin] = acc;
    __syncthreads();
    if (tid < NE) {
        float a = 0.f;
        for (int p = 0; p < 16; ++p) a += s[p * 64 + tid];
        load[tid] = a;
    }
}

// ---------------------------------------------------------------------------
extern "C" void kernel_launch(void* const* d_in, const int* in_sizes, int n_in,
                              void* d_out, int out_size, void* d_ws, size_t ws_size,
                              hipStream_t stream)
{
    const int*   taskID      = (const int*)  d_in[0];
    const float* noise       = (const float*)d_in[1];
    const float* embed_table = (const float*)d_in[2];
    const float* expert_keys = (const float*)d_in[3];
    const float* Wq          = (const float*)d_in[4];
    const float* bq          = (const float*)d_in[5];
    const float* Wk          = (const float*)d_in[6];
    const float* bk          = (const float*)d_in[7];
    const float* Wg          = (const float*)d_in[8];
    const float* bg          = (const float*)d_in[9];
    const float* Wn          = (const float*)d_in[10];
    const float* bn          = (const float*)d_in[11];

    const int B = in_sizes[0];                 // 524288

    float* gates = (float*)d_out;              // B*64
    float* load  = gates + (size_t)B * NE;     // 64

    float* tbl      = (float*)d_ws;                         // 768 floats
    float* partials = (float*)((char*)d_ws + 4096);         // GRID_MAIN*64 floats

    moe_tables<<<1, 384, 0, stream>>>(embed_table, expert_keys,
                                      Wq, bq, Wk, bk, Wg, bg, Wn, bn, tbl);
    moe_gate<<<GRID_MAIN, BLOCK_MAIN, 0, stream>>>(taskID, noise, tbl,
                                                   gates, partials, B);
    moe_load_reduce<<<1, 1024, 0, stream>>>(partials, load, GRID_MAIN);
}

// Round 5
// 308.653 us; speedup vs baseline: 1.0125x; 1.0125x over previous
//
#include <hip/hip_runtime.h>
#include <hip/hip_bf16.h>
#include <math.h>

// MoE gate: B=524288 tokens, E=32, H=4, D=8, NE=64 experts, TOP_K=2.
// Everything up to expert_weight depends ONLY on taskID in [0,6) ->
// precompute clean_logits[6][64] and noise_std[6][64] once (kernel 1),
// then the per-token work is a pure streaming kernel (kernel 2), plus a
// deterministic tree reduction for `load` (kernel 3).
//
// R4 vs R2 (R2: occupancy 69% but BW stuck at 2.5 TB/s -> latency/pipeline
// bound, and NT stores inflated WRITE_SIZE 131->147 MB via half-line writes):
//  - revert nontemporal stores (L2 write-allocate merges the 16B@32B-stride
//    half-line store pairs into full lines)
//  - each block owns a CONTIGUOUS 256-row chunk; 2x(unroll 4) compile-time
//    iteration structure -> 4 iterations of loads in flight (4x MLP)
//  - __launch_bounds__(256,4): trade occupancy (proven useless in R2) for
//    registers to hold the unrolled state

#define NE 64
#define NTASK 6
#define BLOCK_MAIN 256
#define ROWS_PER_BLOCK 256   // 32 rows per iteration x 8 iterations

// ---------------------------------------------------------------------------
// Kernel 1: per-task tables. One block, 384 threads (6 waves = 6 tasks).
// ---------------------------------------------------------------------------
__global__ __launch_bounds__(384)
void moe_tables(const float* __restrict__ embed_table,
                const float* __restrict__ expert_keys,
                const float* __restrict__ Wq, const float* __restrict__ bq,
                const float* __restrict__ Wk, const float* __restrict__ bk,
                const float* __restrict__ Wg, const float* __restrict__ bg,
                const float* __restrict__ Wn, const float* __restrict__ bn,
                float* __restrict__ tbl /* [6][2][64]: clean, noise_std */)
{
    __shared__ float s_ek[1024];   // expert_keys 32x32
    __shared__ float s_wk[1024];   // Wk 32x32
    __shared__ float s_k[1024];    // k[s][e] = expert_keys @ Wk^T + bk (task-indep)
    __shared__ float s_q[NTASK][32];
    __shared__ float s_sc[NTASK][4][32];
    __shared__ float s_ew[NTASK][32];

    const int tid  = threadIdx.x;      // 0..383
    const int wave = tid >> 6;         // task id 0..5
    const int lane = tid & 63;

    for (int i = tid; i < 1024; i += 384) { s_ek[i] = expert_keys[i]; s_wk[i] = Wk[i]; }
    __syncthreads();

    // k = expert_keys @ Wk^T + bk  (shared by all tasks)
    for (int i = tid; i < 1024; i += 384) {
        int s = i >> 5, e = i & 31;
        float acc = bk[e];
        for (int j = 0; j < 32; ++j) acc += s_ek[s*32 + j] * s_wk[e*32 + j];
        s_k[i] = acc;
    }
    __syncthreads();

    // q_t = (embed[t] @ Wq^T + bq) * 1/sqrt(D)
    if (lane < 32) {
        float acc = bq[lane];
        for (int j = 0; j < 32; ++j) acc += embed_table[wave*32 + j] * Wq[lane*32 + j];
        s_q[wave][lane] = acc * 0.35355339059327373f;  // 1/sqrt(8)
    }
    __syncthreads();

    // scores[h][s] = sum_d q[h*8+d] * k[s][h*8+d]
    for (int r = lane; r < 128; r += 64) {
        int h = r >> 5, s = r & 31;
        float acc = 0.f;
        for (int d = 0; d < 8; ++d) acc += s_q[wave][h*8 + d] * s_k[s*32 + h*8 + d];
        s_sc[wave][h][s] = acc;
    }
    __syncthreads();

    // per-head softmax over the 32 experts
    if (lane < 4) {
        int h = lane;
        float m = -1e30f;
        for (int s = 0; s < 32; ++s) m = fmaxf(m, s_sc[wave][h][s]);
        float sum = 0.f;
        for (int s = 0; s < 32; ++s) { float e = expf(s_sc[wave][h][s] - m); s_sc[wave][h][s] = e; sum += e; }
        float inv = 1.f / sum;
        for (int s = 0; s < 32; ++s) s_sc[wave][h][s] *= inv;
    }
    __syncthreads();

    // mean over heads, softmax over experts -> expert_weight
    if (lane == 0) {
        float aw[32];
        float m = -1e30f;
        for (int s = 0; s < 32; ++s) {
            float a = 0.25f * (s_sc[wave][0][s] + s_sc[wave][1][s] +
                               s_sc[wave][2][s] + s_sc[wave][3][s]);
            aw[s] = a; m = fmaxf(m, a);
        }
        float sum = 0.f;
        for (int s = 0; s < 32; ++s) { float e = expf(aw[s] - m); aw[s] = e; sum += e; }
        float inv = 1.f / sum;
        for (int s = 0; s < 32; ++s) s_ew[wave][s] = aw[s] * inv;
    }
    __syncthreads();

    // clean_logits and noise_std per expert (64 outputs, one per lane)
    {
        int j = lane;   // 0..63
        float c = bg[j], n = bn[j];
        for (int s = 0; s < 32; ++s) {
            float w = s_ew[wave][s];
            c += w * Wg[j*32 + s];
            n += w * Wn[j*32 + s];
        }
        // softplus(x) = max(x,0) + log1p(exp(-|x|))
        float sp = fmaxf(n, 0.f) + log1pf(expf(-fabsf(n)));
        tbl[(wave*2    )*64 + j] = c;            // stbl layout: t*128 + j
        tbl[(wave*2 + 1)*64 + j] = sp + 0.01f;   // t*128 + 64 + j (NOISE_EPS)
    }
}

// ---------------------------------------------------------------------------
// Kernel 2: streaming gate kernel. 8 lanes per row; lane gl owns 8 consecutive
// columns [gl*8, gl*8+8) -> two float4 loads/stores per lane, coalesced.
// Top-2 via u64 sortable keys: key = (sortable(v)<<32) | (63-idx), so
// max-key == (value desc, index asc) — the jax.lax.top_k tie rule.
// ---------------------------------------------------------------------------
__device__ __forceinline__ unsigned long long mkkey(float f, int idx) {
    unsigned u  = __float_as_uint(f);
    unsigned su = (u & 0x80000000u) ? ~u : (u | 0x80000000u);
    return ((unsigned long long)su << 32) | (unsigned)(63 - idx);
}
__device__ __forceinline__ float keyval(unsigned long long k) {
    unsigned su = (unsigned)(k >> 32);
    unsigned u  = (su & 0x80000000u) ? (su ^ 0x80000000u) : ~su;
    return __uint_as_float(u);
}
__device__ __forceinline__ unsigned long long umax64(unsigned long long a, unsigned long long b) { return a > b ? a : b; }
__device__ __forceinline__ unsigned long long umin64(unsigned long long a, unsigned long long b) { return a < b ? a : b; }

__global__ __launch_bounds__(BLOCK_MAIN, 4)
void moe_gate(const int* __restrict__ taskID,
              const float* __restrict__ noise,
              const float* __restrict__ tbl,
              float* __restrict__ gates,
              float* __restrict__ partials,
              int B)
{
    __shared__ float stbl[NTASK*128];    // 3 KiB: [task][clean[64] | std[64]]
    __shared__ float sload[NE];

    const int tid = threadIdx.x;
    for (int i = tid; i < NTASK*128; i += BLOCK_MAIN) stbl[i] = tbl[i];
    if (tid < NE) sload[tid] = 0.f;
    __syncthreads();

    const int sub = tid >> 3;         // 0..31: row slot within block
    const int gl  = tid & 7;          // lane within 8-lane row group
    const int c0  = gl * 8;           // first of 8 owned columns

    const long base = (long)blockIdx.x * ROWS_PER_BLOCK + sub;

    #pragma unroll
    for (int half = 0; half < 2; ++half) {
        #pragma unroll
        for (int it = 0; it < 4; ++it) {
            const long row = base + (half * 4 + it) * 32;
            if (row >= B) continue;

            const int t = taskID[row];
            const float* cl = &stbl[t * 128];

            const float4* np = (const float4*)(noise + row * 64 + c0);
            float4 nz0 = np[0];
            float4 nz1 = np[1];
            float4 cc0 = *(const float4*)(cl + c0);
            float4 cc1 = *(const float4*)(cl + c0 + 4);
            float4 ss0 = *(const float4*)(cl + 64 + c0);
            float4 ss1 = *(const float4*)(cl + 64 + c0 + 4);

            float v[8];
            v[0] = fmaf(nz0.x, ss0.x, cc0.x);
            v[1] = fmaf(nz0.y, ss0.y, cc0.y);
            v[2] = fmaf(nz0.z, ss0.z, cc0.z);
            v[3] = fmaf(nz0.w, ss0.w, cc0.w);
            v[4] = fmaf(nz1.x, ss1.x, cc1.x);
            v[5] = fmaf(nz1.y, ss1.y, cc1.y);
            v[6] = fmaf(nz1.z, ss1.z, cc1.z);
            v[7] = fmaf(nz1.w, ss1.w, cc1.w);

            // local top-2 of 8
            unsigned long long k1 = mkkey(v[0], c0), k2 = 0ull;
            #pragma unroll
            for (int j = 1; j < 8; ++j) {
                unsigned long long k = mkkey(v[j], c0 + j);
                if (k > k1)      { k2 = k1; k1 = k; }
                else if (k > k2) { k2 = k; }
            }

            // butterfly merge across the 8-lane group (masks 1,2,4 in-group)
            #pragma unroll
            for (int m = 1; m < 8; m <<= 1) {
                unsigned long long p1 = __shfl_xor((unsigned long long)k1, m);
                unsigned long long p2 = __shfl_xor((unsigned long long)k2, m);
                unsigned long long hi = umax64(k1, p1);
                unsigned long long lo = umin64(k1, p1);
                k2 = umax64(lo, umax64(k2, p2));
                k1 = hi;
            }

            const int i1 = 63 - (int)(k1 & 63u);
            const int i2 = 63 - (int)(k2 & 63u);
            const float v1 = keyval(k1);
            const float v2 = keyval(k2);

            const float e   = expf(v2 - v1);
            const float inv = 1.f / (1.f + e);
            const float g1  = inv, g2 = e * inv;

            float o[8];
            #pragma unroll
            for (int j = 0; j < 8; ++j) {
                const int col = c0 + j;
                o[j] = (col == i1) ? g1 : ((col == i2) ? g2 : 0.f);
            }
            *(float4*)(gates + row * 64 + c0)     = make_float4(o[0], o[1], o[2], o[3]);
            *(float4*)(gates + row * 64 + c0 + 4) = make_float4(o[4], o[5], o[6], o[7]);

            if (gl == 0) {
                atomicAdd(&sload[i1], g1);
                atomicAdd(&sload[i2], g2);
            }
        }
    }
    __syncthreads();
    if (tid < NE) partials[(long)blockIdx.x * NE + tid] = sload[tid];
}

// ---------------------------------------------------------------------------
// Kernel 3: deterministic reduction of per-block partials -> load[64].
// ---------------------------------------------------------------------------
__global__ __launch_bounds__(1024)
void moe_load_reduce(const float* __restrict__ partials,
                     float* __restrict__ load, int nparts)
{
    __shared__ float s[1024];
    const int tid  = threadIdx.x;       // 0..1023
    const int bin  = tid & 63;
    const int part = tid >> 6;          // 0..15
    const int per  = (nparts + 15) >> 4;  // partials per group (ceil)
    float acc = 0.f;
    for (int p = part * per; p < (part + 1) * per && p < nparts; ++p)
        acc += partials[(long)p * NE + bin];
    s[part * 64 + bin] = acc;
    __syncthreads();
    if (tid < NE) {
        float a = 0.f;
        for (int p = 0; p < 16; ++p) a += s[p * 64 + tid];
        load[tid] = a;
    }
}

// ---------------------------------------------------------------------------
extern "C" void kernel_launch(void* const* d_in, const int* in_sizes, int n_in,
                              void* d_out, int out_size, void* d_ws, size_t ws_size,
                              hipStream_t stream)
{
    const int*   taskID      = (const int*)  d_in[0];
    const float* noise       = (const float*)d_in[1];
    const float* embed_table = (const float*)d_in[2];
    const float* expert_keys = (const float*)d_in[3];
    const float* Wq          = (const float*)d_in[4];
    const float* bq          = (const float*)d_in[5];
    const float* Wk          = (const float*)d_in[6];
    const float* bk          = (const float*)d_in[7];
    const float* Wg          = (const float*)d_in[8];
    const float* bg          = (const float*)d_in[9];
    const float* Wn          = (const float*)d_in[10];
    const float* bn          = (const float*)d_in[11];

    const int B = in_sizes[0];                 // 524288

    float* gates = (float*)d_out;              // B*64
    float* load  = gates + (size_t)B * NE;     // 64

    float* tbl      = (float*)d_ws;                         // 768 floats
    float* partials = (float*)((char*)d_ws + 4096);         // grid*64 floats

    const int grid = (B + ROWS_PER_BLOCK - 1) / ROWS_PER_BLOCK;   // 2048

    moe_tables<<<1, 384, 0, stream>>>(embed_table, expert_keys,
                                      Wq, bq, Wk, bk, Wg, bg, Wn, bn, tbl);
    moe_gate<<<grid, BLOCK_MAIN, 0, stream>>>(taskID, noise, tbl,
                                              gates, partials, B);
    moe_load_reduce<<<1, 1024, 0, stream>>>(partials, load, grid);
}

// Round 7
// 308.282 us; speedup vs baseline: 1.0137x; 1.0012x over previous
//
#include <hip/hip_runtime.h>
#include <hip/hip_bf16.h>
#include <math.h>

// MoE gate: B=524288 tokens, E=32, H=4, D=8, NE=64 experts, TOP_K=2.
// Everything up to expert_weight depends ONLY on taskID in [0,6) ->
// precompute clean_logits[6][64] and noise_std[6][64] once (kernel 1),
// then the per-token work is a pure streaming kernel (kernel 2), plus a
// deterministic tree reduction for `load` (kernel 3).
//
// R5 vs R4: R4's #pragma unroll never materialized (VGPR stayed 32 -> the
// compiler serialized the loop; per-iter bounds-branch + atomics blocked
// load hoisting). R5 hand-splits each 4-iteration group into an explicit
// LOAD PHASE (all taskID + noise loads issued into static register arrays,
// no intervening branches) and a COMPUTE PHASE. Block-level bounds check
// (all blocks full when B % 256 == 0). Target: 8 outstanding float4
// noise-loads per lane -> ~9KB/wave in flight (was ~2KB).
// R6: identical to R5 (R5 never ran — broker timeout).

#define NE 64
#define NTASK 6
#define BLOCK_MAIN 256
#define ROWS_PER_BLOCK 256   // 32 rows per iteration x 8 iterations

typedef float f32x4 __attribute__((ext_vector_type(4)));

// ---------------------------------------------------------------------------
// Kernel 1: per-task tables. One block, 384 threads (6 waves = 6 tasks).
// ---------------------------------------------------------------------------
__global__ __launch_bounds__(384)
void moe_tables(const float* __restrict__ embed_table,
                const float* __restrict__ expert_keys,
                const float* __restrict__ Wq, const float* __restrict__ bq,
                const float* __restrict__ Wk, const float* __restrict__ bk,
                const float* __restrict__ Wg, const float* __restrict__ bg,
                const float* __restrict__ Wn, const float* __restrict__ bn,
                float* __restrict__ tbl /* [6][2][64]: clean, noise_std */)
{
    __shared__ float s_ek[1024];   // expert_keys 32x32
    __shared__ float s_wk[1024];   // Wk 32x32
    __shared__ float s_k[1024];    // k[s][e] = expert_keys @ Wk^T + bk (task-indep)
    __shared__ float s_q[NTASK][32];
    __shared__ float s_sc[NTASK][4][32];
    __shared__ float s_ew[NTASK][32];

    const int tid  = threadIdx.x;      // 0..383
    const int wave = tid >> 6;         // task id 0..5
    const int lane = tid & 63;

    for (int i = tid; i < 1024; i += 384) { s_ek[i] = expert_keys[i]; s_wk[i] = Wk[i]; }
    __syncthreads();

    // k = expert_keys @ Wk^T + bk  (shared by all tasks)
    for (int i = tid; i < 1024; i += 384) {
        int s = i >> 5, e = i & 31;
        float acc = bk[e];
        for (int j = 0; j < 32; ++j) acc += s_ek[s*32 + j] * s_wk[e*32 + j];
        s_k[i] = acc;
    }
    __syncthreads();

    // q_t = (embed[t] @ Wq^T + bq) * 1/sqrt(D)
    if (lane < 32) {
        float acc = bq[lane];
        for (int j = 0; j < 32; ++j) acc += embed_table[wave*32 + j] * Wq[lane*32 + j];
        s_q[wave][lane] = acc * 0.35355339059327373f;  // 1/sqrt(8)
    }
    __syncthreads();

    // scores[h][s] = sum_d q[h*8+d] * k[s][h*8+d]
    for (int r = lane; r < 128; r += 64) {
        int h = r >> 5, s = r & 31;
        float acc = 0.f;
        for (int d = 0; d < 8; ++d) acc += s_q[wave][h*8 + d] * s_k[s*32 + h*8 + d];
        s_sc[wave][h][s] = acc;
    }
    __syncthreads();

    // per-head softmax over the 32 experts
    if (lane < 4) {
        int h = lane;
        float m = -1e30f;
        for (int s = 0; s < 32; ++s) m = fmaxf(m, s_sc[wave][h][s]);
        float sum = 0.f;
        for (int s = 0; s < 32; ++s) { float e = expf(s_sc[wave][h][s] - m); s_sc[wave][h][s] = e; sum += e; }
        float inv = 1.f / sum;
        for (int s = 0; s < 32; ++s) s_sc[wave][h][s] *= inv;
    }
    __syncthreads();

    // mean over heads, softmax over experts -> expert_weight
    if (lane == 0) {
        float aw[32];
        float m = -1e30f;
        for (int s = 0; s < 32; ++s) {
            float a = 0.25f * (s_sc[wave][0][s] + s_sc[wave][1][s] +
                               s_sc[wave][2][s] + s_sc[wave][3][s]);
            aw[s] = a; m = fmaxf(m, a);
        }
        float sum = 0.f;
        for (int s = 0; s < 32; ++s) { float e = expf(aw[s] - m); aw[s] = e; sum += e; }
        float inv = 1.f / sum;
        for (int s = 0; s < 32; ++s) s_ew[wave][s] = aw[s] * inv;
    }
    __syncthreads();

    // clean_logits and noise_std per expert (64 outputs, one per lane)
    {
        int j = lane;   // 0..63
        float c = bg[j], n = bn[j];
        for (int s = 0; s < 32; ++s) {
            float w = s_ew[wave][s];
            c += w * Wg[j*32 + s];
            n += w * Wn[j*32 + s];
        }
        // softplus(x) = max(x,0) + log1p(exp(-|x|))
        float sp = fmaxf(n, 0.f) + log1pf(expf(-fabsf(n)));
        tbl[(wave*2    )*64 + j] = c;            // stbl layout: t*128 + j
        tbl[(wave*2 + 1)*64 + j] = sp + 0.01f;   // t*128 + 64 + j (NOISE_EPS)
    }
}

// ---------------------------------------------------------------------------
// Kernel 2: streaming gate kernel. 8 lanes per row; lane gl owns 8 consecutive
// columns [gl*8, gl*8+8) -> two float4 loads/stores per lane, coalesced.
// Top-2 via u64 sortable keys: key = (sortable(v)<<32) | (63-idx), so
// max-key == (value desc, index asc) — the jax.lax.top_k tie rule.
// ---------------------------------------------------------------------------
__device__ __forceinline__ unsigned long long mkkey(float f, int idx) {
    unsigned u  = __float_as_uint(f);
    unsigned su = (u & 0x80000000u) ? ~u : (u | 0x80000000u);
    return ((unsigned long long)su << 32) | (unsigned)(63 - idx);
}
__device__ __forceinline__ float keyval(unsigned long long k) {
    unsigned su = (unsigned)(k >> 32);
    unsigned u  = (su & 0x80000000u) ? (su ^ 0x80000000u) : ~su;
    return __uint_as_float(u);
}
__device__ __forceinline__ unsigned long long umax64(unsigned long long a, unsigned long long b) { return a > b ? a : b; }
__device__ __forceinline__ unsigned long long umin64(unsigned long long a, unsigned long long b) { return a < b ? a : b; }

// per-row pipeline after loads are in registers
__device__ __forceinline__ void gate_row(float4 nz0, float4 nz1,
                                         const float* __restrict__ cl,
                                         int c0, int gl,
                                         float* __restrict__ gptr,
                                         float* __restrict__ sload)
{
    float4 cc0 = *(const float4*)(cl + c0);
    float4 cc1 = *(const float4*)(cl + c0 + 4);
    float4 ss0 = *(const float4*)(cl + 64 + c0);
    float4 ss1 = *(const float4*)(cl + 64 + c0 + 4);

    float v[8];
    v[0] = fmaf(nz0.x, ss0.x, cc0.x);
    v[1] = fmaf(nz0.y, ss0.y, cc0.y);
    v[2] = fmaf(nz0.z, ss0.z, cc0.z);
    v[3] = fmaf(nz0.w, ss0.w, cc0.w);
    v[4] = fmaf(nz1.x, ss1.x, cc1.x);
    v[5] = fmaf(nz1.y, ss1.y, cc1.y);
    v[6] = fmaf(nz1.z, ss1.z, cc1.z);
    v[7] = fmaf(nz1.w, ss1.w, cc1.w);

    // local top-2 of 8
    unsigned long long k1 = mkkey(v[0], c0), k2 = 0ull;
    #pragma unroll
    for (int j = 1; j < 8; ++j) {
        unsigned long long k = mkkey(v[j], c0 + j);
        if (k > k1)      { k2 = k1; k1 = k; }
        else if (k > k2) { k2 = k; }
    }

    // butterfly merge across the 8-lane group (masks 1,2,4 in-group)
    #pragma unroll
    for (int m = 1; m < 8; m <<= 1) {
        unsigned long long p1 = __shfl_xor((unsigned long long)k1, m);
        unsigned long long p2 = __shfl_xor((unsigned long long)k2, m);
        unsigned long long hi = umax64(k1, p1);
        unsigned long long lo = umin64(k1, p1);
        k2 = umax64(lo, umax64(k2, p2));
        k1 = hi;
    }

    const int i1 = 63 - (int)(k1 & 63u);
    const int i2 = 63 - (int)(k2 & 63u);
    const float v1 = keyval(k1);
    const float v2 = keyval(k2);

    const float e   = expf(v2 - v1);
    const float inv = 1.f / (1.f + e);
    const float g1  = inv, g2 = e * inv;

    float o[8];
    #pragma unroll
    for (int j = 0; j < 8; ++j) {
        const int col = c0 + j;
        o[j] = (col == i1) ? g1 : ((col == i2) ? g2 : 0.f);
    }
    *(float4*)(gptr)     = make_float4(o[0], o[1], o[2], o[3]);
    *(float4*)(gptr + 4) = make_float4(o[4], o[5], o[6], o[7]);

    if (gl == 0) {
        atomicAdd(&sload[i1], g1);
        atomicAdd(&sload[i2], g2);
    }
}

__global__ __launch_bounds__(BLOCK_MAIN, 4)
void moe_gate(const int* __restrict__ taskID,
              const float* __restrict__ noise,
              const float* __restrict__ tbl,
              float* __restrict__ gates,
              float* __restrict__ partials,
              int B)
{
    __shared__ float stbl[NTASK*128];    // 3 KiB: [task][clean[64] | std[64]]
    __shared__ float sload[NE];

    const int tid = threadIdx.x;
    for (int i = tid; i < NTASK*128; i += BLOCK_MAIN) stbl[i] = tbl[i];
    if (tid < NE) sload[tid] = 0.f;
    __syncthreads();

    const int sub = tid >> 3;         // 0..31: row slot within block
    const int gl  = tid & 7;          // lane within 8-lane row group
    const int c0  = gl * 8;           // first of 8 owned columns

    const long base = (long)blockIdx.x * ROWS_PER_BLOCK + sub;
    const bool full = (base + 7 * 32) < B;   // all 8 iterations in bounds

    if (full) {
        #pragma unroll
        for (int half = 0; half < 2; ++half) {
            // ---------- LOAD PHASE: 4 iterations, no branches ----------
            int    t[4];
            float4 nz0[4], nz1[4];
            {
                const long r0 = base + (half * 4) * 32;
                t[0] = taskID[r0];       t[1] = taskID[r0 + 32];
                t[2] = taskID[r0 + 64];  t[3] = taskID[r0 + 96];
                const float4* np0 = (const float4*)(noise + r0 * 64 + c0);
                const float4* np1 = (const float4*)(noise + (r0 + 32) * 64 + c0);
                const float4* np2 = (const float4*)(noise + (r0 + 64) * 64 + c0);
                const float4* np3 = (const float4*)(noise + (r0 + 96) * 64 + c0);
                nz0[0] = np0[0]; nz1[0] = np0[1];
                nz0[1] = np1[0]; nz1[1] = np1[1];
                nz0[2] = np2[0]; nz1[2] = np2[1];
                nz0[3] = np3[0]; nz1[3] = np3[1];
            }
            // ---------- COMPUTE PHASE ----------
            #pragma unroll
            for (int it = 0; it < 4; ++it) {
                const long row = base + (half * 4 + it) * 32;
                gate_row(nz0[it], nz1[it], &stbl[t[it] * 128], c0, gl,
                         gates + row * 64 + c0, sload);
            }
        }
    } else {
        for (int k = 0; k < 8; ++k) {
            const long row = base + k * 32;
            if (row >= B) break;
            const int t = taskID[row];
            const float4* np = (const float4*)(noise + row * 64 + c0);
            float4 nz0 = np[0], nz1 = np[1];
            gate_row(nz0, nz1, &stbl[t * 128], c0, gl,
                     gates + row * 64 + c0, sload);
        }
    }

    __syncthreads();
    if (tid < NE) partials[(long)blockIdx.x * NE + tid] = sload[tid];
}

// ---------------------------------------------------------------------------
// Kernel 3: deterministic reduction of per-block partials -> load[64].
// ---------------------------------------------------------------------------
__global__ __launch_bounds__(1024)
void moe_load_reduce(const float* __restrict__ partials,
                     float* __restrict__ load, int nparts)
{
    __shared__ float s[1024];
    const int tid  = threadIdx.x;       // 0..1023
    const int bin  = tid & 63;
    const int part = tid >> 6;          // 0..15
    const int per  = (nparts + 15) >> 4;  // partials per group (ceil)
    float acc = 0.f;
    for (int p = part * per; p < (part + 1) * per && p < nparts; ++p)
        acc += partials[(long)p * NE + bin];
    s[part * 64 + bin] = acc;
    __syncthreads();
    if (tid < NE) {
        float a = 0.f;
        for (int p = 0; p < 16; ++p) a += s[p * 64 + tid];
        load[tid] = a;
    }
}

// ---------------------------------------------------------------------------
extern "C" void kernel_launch(void* const* d_in, const int* in_sizes, int n_in,
                              void* d_out, int out_size, void* d_ws, size_t ws_size,
                              hipStream_t stream)
{
    const int*   taskID      = (const int*)  d_in[0];
    const float* noise       = (const float*)d_in[1];
    const float* embed_table = (const float*)d_in[2];
    const float* expert_keys = (const float*)d_in[3];
    const float* Wq          = (const float*)d_in[4];
    const float* bq          = (const float*)d_in[5];
    const float* Wk          = (const float*)d_in[6];
    const float* bk          = (const float*)d_in[7];
    const float* Wg          = (const float*)d_in[8];
    const float* bg          = (const float*)d_in[9];
    const float* Wn          = (const float*)d_in[10];
    const float* bn          = (const float*)d_in[11];

    const int B = in_sizes[0];                 // 524288

    float* gates = (float*)d_out;              // B*64
    float* load  = gates + (size_t)B * NE;     // 64

    float* tbl      = (float*)d_ws;                         // 768 floats
    float* partials = (float*)((char*)d_ws + 4096);         // grid*64 floats

    const int grid = (B + ROWS_PER_BLOCK - 1) / ROWS_PER_BLOCK;   // 2048

    moe_tables<<<1, 384, 0, stream>>>(embed_table, expert_keys,
                                      Wq, bq, Wk, bk, Wg, bg, Wn, bn, tbl);
    moe_gate<<<grid, BLOCK_MAIN, 0, stream>>>(taskID, noise, tbl,
                                              gates, partials, B);
    moe_load_reduce<<<1, 1024, 0, stream>>>(partials, load, grid);
}